// Round 17
// baseline (121.051 us; speedup 1.0000x reference)
//
#include <hip/hip_runtime.h>
#include <hip/hip_fp8.h>

typedef __attribute__((ext_vector_type(4))) float f32x4;
typedef __attribute__((ext_vector_type(4))) unsigned u32x4;

// ---- d_out scratch (float offsets), consumed by k1est before k2 overwrites:
//   xa_t fp8[16777216B] -> floats [0, 4194304)        tiled [64 bm][128 kt][64 r][32 k] swz
//   wb_t fp8[ 4194304B] -> floats [4194304, 5242880)  tiled [ 8 bn][128 kt][128 n][32 k] swz (W1*64)
// ---- d_ws layout (bytes):
//   plogit f32[4096*16] [0, 262144)      exact relu'd N-partials (unique writer, bn*2+wn)
//   thr    u32[4096]    [262144, 278528) kth-smallest |x| bit patterns
//   l1rows f64[4096]    [278528, 311296)

__device__ __forceinline__ unsigned char f2fp8(float f) {
    return (unsigned char)__hip_cvt_float_to_fp8(f, __HIP_SATFINITE, __HIP_E4M3);
}

__device__ __forceinline__ void gl16(const void* g, void* l) {
    __builtin_amdgcn_global_load_lds(
        (const __attribute__((address_space(1))) void*)g,
        (__attribute__((address_space(3))) void*)l, 16, 0, 0);
}

// ---------------- k0a: x (fp32 [4096][4096]) -> xa_t (fp8 e4m3, 64-row K-tiled + swz)
__global__ __launch_bounds__(256) void k0a_cvtx(const float* __restrict__ x,
                                                unsigned char* __restrict__ xa_t)
{
    const int bm = blockIdx.x;                // 0..63 (64-row group)
    const int ktbase = blockIdx.y * 16;       // 8 y-blocks x 16 kt
    const int t = threadIdx.x;
    const int rr = t >> 2, q = t & 3;         // row 0..63, k-oct 0..3
    const int kgp = q ^ ((rr >> 1) & 3);
    const size_t rowoff = (size_t)(bm * 64 + rr) * 4096;

    #pragma unroll
    for (int i = 0; i < 16; i++) {
        const int kt = ktbase + i;
        const float* src = x + rowoff + kt * 32 + q * 8;
        float4 v0 = *(const float4*)src;
        float4 v1 = *(const float4*)(src + 4);
        union { unsigned char c[8]; uint2 u; } o;
        o.c[0] = f2fp8(v0.x); o.c[1] = f2fp8(v0.y);
        o.c[2] = f2fp8(v0.z); o.c[3] = f2fp8(v0.w);
        o.c[4] = f2fp8(v1.x); o.c[5] = f2fp8(v1.y);
        o.c[6] = f2fp8(v1.z); o.c[7] = f2fp8(v1.w);
        *(uint2*)(xa_t + ((size_t)(bm * 128 + kt) * 64 + rr) * 32 + kgp * 8) = o.u;
    }
}

// ---------------- k0b: W1 [4096][1024] fp32 -> wb_t (fp8 of 64*W1, transposed tiled + swz)
__global__ __launch_bounds__(256) void k0b_cvtw(const float* __restrict__ W1,
                                                unsigned char* __restrict__ wb_t)
{
    __shared__ float ls[32][128];
    const int bx = blockIdx.x;                // 1024 = 8 bn x 128 kt
    const int bn = bx >> 7, kt = bx & 127;
    const int t = threadIdx.x;

    #pragma unroll
    for (int i = 0; i < 4; i++) {
        int s = t + i * 256;                  // 1024 float4 slots
        int r = s >> 5, c4 = s & 31;
        *(float4*)&ls[r][c4 * 4] =
            *(const float4*)(W1 + (size_t)(kt * 32 + r) * 1024 + bn * 128 + c4 * 4);
    }
    __syncthreads();

    const int n = t >> 1, half = t & 1;
    #pragma unroll
    for (int kg2 = 0; kg2 < 2; kg2++) {
        const int kg = half * 2 + kg2;
        const int kgp = kg ^ ((n >> 1) & 3);
        union { unsigned char c[8]; uint2 u; } o;
        #pragma unroll
        for (int j = 0; j < 8; j++) o.c[j] = f2fp8(ls[kg * 8 + j][n] * 64.0f);
        *(uint2*)(wb_t + (size_t)(bn * 128 + kt) * 4096 + n * 32 + kgp * 8) = o.u;
    }
}

// ---------------- k1est: fp8 MFMA, BM=64 x BN=128, FULL K (exact relu), N-split partials.
// 8 waves (512 thr): wave w -> rows (w&3)*16, cols (w>>2)*64. Waves 0-3 stage with
// counted vmcnt(6) quad-buffer schedule; waves 4-7 compute-only. R13-exact.
__global__ __launch_bounds__(512, 4) void k1est(const unsigned char* __restrict__ xa_t,
                                                const unsigned char* __restrict__ wb_t,
                                                const float* __restrict__ b1,
                                                const float* __restrict__ W2,
                                                float* __restrict__ plogit)
{
    __shared__ alignas(16) unsigned char Ab[4][4096];
    __shared__ alignas(16) unsigned char Bb[4][8192];

    const int bid = blockIdx.x;                      // 512 blocks
    const int wgid = (bid & 7) * 64 + (bid >> 3);    // bijective, XCD-chunked
    const int bn = wgid >> 6, bm = wgid & 63;        // one bn per XCD (L2-pinned W)
    const int tid = threadIdx.x;
    const int l = tid & 63, w = tid >> 6;
    const int wm = w & 3, wn = w >> 2;
    const int arow = l & 15, kg = l >> 4;
    const int kgs = kg ^ ((arow >> 1) & 3);
    const bool stager = (w < 4);                     // tid < 256

    const unsigned char* abase = xa_t + (size_t)bm * 128 * 2048;
    const unsigned char* bbase = wb_t + (size_t)bn * 128 * 4096;

    f32x4 acc[4];
    #pragma unroll
    for (int j = 0; j < 4; j++) acc[j] = (f32x4)0.0f;

#define ISSUE(step, buf)                                                          \
    if (stager) {                                                                 \
        gl16(abase + (size_t)(step) * 4096 + tid * 16, &Ab[buf][tid * 16]);       \
        gl16(bbase + (size_t)(step) * 8192 + tid * 16, &Bb[buf][tid * 16]);       \
        gl16(bbase + (size_t)(step) * 8192 + (256 + tid) * 16,                    \
             &Bb[buf][(256 + tid) * 16]);                                         \
    }

    ISSUE(0, 0);
    ISSUE(1, 1);

    for (int t = 0; t < 64; t++) {
        const int buf = t & 3;
        if (t <= 61) {
            ISSUE(t + 2, (t + 2) & 3);
            asm volatile("s_waitcnt vmcnt(6)" ::: "memory");
        } else if (t == 62) {
            asm volatile("s_waitcnt vmcnt(3)" ::: "memory");
        } else {
            asm volatile("s_waitcnt vmcnt(0)" ::: "memory");
        }
        __builtin_amdgcn_s_barrier();
        __builtin_amdgcn_sched_barrier(0);

        #pragma unroll
        for (int j = 0; j < 2; j++) {
            long af = *(const long*)&Ab[buf][j * 2048 + (wm * 16 + arow) * 32 + kgs * 8];
            #pragma unroll
            for (int nf = 0; nf < 4; nf++) {
                long bf = *(const long*)&Bb[buf][j * 4096 +
                                                 (wn * 64 + nf * 16 + arow) * 32 + kgs * 8];
                acc[nf] = __builtin_amdgcn_mfma_f32_16x16x32_fp8_fp8(af, bf, acc[nf], 0, 0, 0);
            }
        }
    }
#undef ISSUE

    // epilogue: EXACT relu over full-K h, dot W2 over this wave's 64 cols.
    // C/D layout (m89): col = lane&15 (N idx), row = (lane>>4)*4 + i (M idx)
    float p[4] = {0.0f, 0.0f, 0.0f, 0.0f};
    #pragma unroll
    for (int nf = 0; nf < 4; nf++) {
        const int n = bn * 128 + wn * 64 + nf * 16 + arow;
        const float bb = b1[n], ww = W2[n];
        #pragma unroll
        for (int i = 0; i < 4; i++) {
            float h = acc[nf][i] * 0.015625f + bb;   // undo W1*64 scale
            if (h > 0.0f) p[i] += h * ww;
        }
    }
    #pragma unroll
    for (int i = 0; i < 4; i++) {
        #pragma unroll
        for (int o = 1; o < 16; o <<= 1) p[i] += __shfl_xor(p[i], o, 64);
        if (arow == 0) {
            const int row = bm * 64 + wm * 16 + kg * 4 + i;
            plogit[(size_t)row * 16 + bn * 2 + wn] = p[i];   // unique writer
        }
    }
}

// ---------------- k2a: per-row k + radix select -> thr[row]. SELECT ONLY (no big writes).
// Row register-cached; radix 11+8+8+4 with scan-based compaction. Same arithmetic as
// R15 -> bit-identical thr.
__global__ __launch_bounds__(256) void k2a_sel(const float* __restrict__ x,
                                               const float* __restrict__ plogit,
                                               const float* __restrict__ b2,
                                               unsigned* __restrict__ thr_arr,
                                               float* __restrict__ out_spars)
{
    __shared__ unsigned hist[2048];
    __shared__ unsigned cand[512];
    __shared__ unsigned wsum[4];
    __shared__ unsigned sel_s, selexc_s;
    __shared__ int k_s;

    const int row = blockIdx.x;
    const int tid = threadIdx.x;
    const int lane = tid & 63, wid = tid >> 6;
    const float* xr = x + (size_t)row * 4096;

    for (int i = tid; i < 2048; i += 256) hist[i] = 0;
    if (tid == 0) {
        float lg = 0.0f;
        #pragma unroll
        for (int t = 0; t < 16; t++) lg += plogit[(size_t)row * 16 + t];
        double s  = 1.0 / (1.0 + exp(-(double)(lg + b2[0])));
        double sp = 0.05 + 0.25 * s;
        int k = (int)rint(4096.0 * (1.0 - sp));
        if (k < 1) k = 1;
        if (k > 4096) k = 4096;
        k_s = k;
        out_spars[row] = (float)sp;
    }
    __syncthreads();

    // ---- load row into registers + pass-0 histogram (11-bit bins, bits 30:20)
    uint4 rv[4];
    #pragma unroll
    for (int j = 0; j < 4; j++) {
        rv[j] = ((const uint4*)xr)[tid + j * 256];
        atomicAdd(&hist[(rv[j].x & 0x7fffffffu) >> 20], 1u);
        atomicAdd(&hist[(rv[j].y & 0x7fffffffu) >> 20], 1u);
        atomicAdd(&hist[(rv[j].z & 0x7fffffffu) >> 20], 1u);
        atomicAdd(&hist[(rv[j].w & 0x7fffffffu) >> 20], 1u);
    }
    __syncthreads();

    int krem = k_s;
    unsigned prefix = 0;
    {
        const unsigned base = tid * 8;
        unsigned bl[8];
        unsigned v = 0;
        #pragma unroll
        for (int j = 0; j < 8; j++) { bl[j] = hist[base + j]; v += bl[j]; }
        unsigned sc = v;
        #pragma unroll
        for (int o = 1; o < 64; o <<= 1) {
            unsigned n = __shfl_up(sc, o, 64);
            if (lane >= o) sc += n;
        }
        if (lane == 63) wsum[wid] = sc;
        __syncthreads();
        unsigned off = 0;
        for (int ww = 0; ww < wid; ww++) off += wsum[ww];
        sc += off;
        unsigned exc = sc - v;
        if ((int)sc >= krem && (int)exc < krem) {
            unsigned run = exc;
            #pragma unroll
            for (int j = 0; j < 8; j++) {
                if ((int)run < krem && (int)(run + bl[j]) >= krem) {
                    sel_s = base + j; selexc_s = run;
                }
                run += bl[j];
            }
        }
        __syncthreads();
        prefix = sel_s;
        krem -= (int)selexc_s;
        __syncthreads();
    }

    // ---- compact candidates matching the 11-bit prefix via exact block scan
    int cntm = 0;
    #pragma unroll
    for (int j = 0; j < 4; j++)
        #pragma unroll
        for (int e = 0; e < 4; e++) {
            unsigned a = (&rv[j].x)[e] & 0x7fffffffu;
            if ((a >> 20) == prefix) cntm++;
        }
    unsigned sc2 = (unsigned)cntm;
    #pragma unroll
    for (int o = 1; o < 64; o <<= 1) {
        unsigned n = __shfl_up(sc2, o, 64);
        if (lane >= o) sc2 += n;
    }
    if (lane == 63) wsum[wid] = sc2;
    __syncthreads();
    unsigned off2 = 0;
    for (int ww = 0; ww < wid; ww++) off2 += wsum[ww];
    unsigned pos = sc2 + off2 - (unsigned)cntm;     // exclusive prefix
    const int nc = (int)(wsum[0] + wsum[1] + wsum[2] + wsum[3]);
    #pragma unroll
    for (int j = 0; j < 4; j++)
        #pragma unroll
        for (int e = 0; e < 4; e++) {
            unsigned a = (&rv[j].x)[e] & 0x7fffffffu;
            if ((a >> 20) == prefix) { if (pos < 512) cand[pos] = a; pos++; }
        }
    __syncthreads();
    const bool usec = (nc <= 512);

    // ---- passes 1-3: 8/8/4 bits among prefix-matched elements
    #pragma unroll
    for (int p = 0; p < 3; p++) {
        const int shift = (p == 0) ? 12 : (p == 1) ? 4 : 0;
        const int width = (p == 2) ? 4 : 8;
        const int nb = 1 << width;
        const int topshift = shift + width;
        if (tid < nb) hist[tid] = 0;
        __syncthreads();
        if (usec) {
            for (int i = tid; i < nc; i += 256) {
                unsigned a = cand[i];
                if ((a >> topshift) == prefix)
                    atomicAdd(&hist[(a >> shift) & (nb - 1)], 1u);
            }
        } else {
            #pragma unroll
            for (int j = 0; j < 4; j++) {
                #pragma unroll
                for (int e = 0; e < 4; e++) {
                    unsigned a = (&rv[j].x)[e] & 0x7fffffffu;
                    if ((a >> topshift) == prefix)
                        atomicAdd(&hist[(a >> shift) & (nb - 1)], 1u);
                }
            }
        }
        __syncthreads();
        unsigned v = (tid < nb) ? hist[tid] : 0;
        unsigned sc = v;
        #pragma unroll
        for (int o = 1; o < 64; o <<= 1) {
            unsigned n = __shfl_up(sc, o, 64);
            if (lane >= o) sc += n;
        }
        if (lane == 63) wsum[wid] = sc;
        __syncthreads();
        unsigned off = 0;
        for (int ww = 0; ww < wid; ww++) off += wsum[ww];
        sc += off;
        unsigned exc = sc - v;
        if ((int)sc >= krem && (int)exc < krem) { sel_s = (unsigned)tid; selexc_s = exc; }
        __syncthreads();
        prefix = (prefix << width) | sel_s;
        krem -= (int)selexc_s;
        __syncthreads();
    }

    if (tid == 0) thr_arr[row] = prefix;   // kth smallest |x| bit pattern (31 bits)
}

// ---------------- k2b: barrier-free streaming apply. Reads x (L3-warm from k2a),
// nontemporal-stores sparse+mask (128MB, never re-read), per-row cnt/l1 reduce.
__global__ __launch_bounds__(256) void k2b_apply(const float* __restrict__ x,
                                                 const unsigned* __restrict__ thr_arr,
                                                 float* __restrict__ out_sparse,
                                                 float* __restrict__ out_mask,
                                                 float* __restrict__ out_actual,
                                                 double* __restrict__ l1rows)
{
    __shared__ int cnt_w[4];
    __shared__ double l1_w[4];

    const int row = blockIdx.x;
    const int tid = threadIdx.x;
    const int lane = tid & 63, wid = tid >> 6;
    const unsigned thr = thr_arr[row];
    const float* xr = x + (size_t)row * 4096;
    f32x4* os = (f32x4*)(out_sparse + (size_t)row * 4096);
    f32x4* om = (f32x4*)(out_mask + (size_t)row * 4096);

    int cnt = 0;
    double l1 = 0.0;
    #pragma unroll
    for (int j = 0; j < 4; j++) {
        u32x4 bv = ((const u32x4*)xr)[tid + j * 256];
        f32x4 sv, mv;
        #pragma unroll
        for (int e = 0; e < 4; e++) {
            unsigned b = bv[e];
            unsigned a = b & 0x7fffffffu;
            bool m = a > thr;
            sv[e] = m ? __uint_as_float(b) : 0.0f;
            mv[e] = m ? 1.0f : 0.0f;
            if (m) { cnt++; l1 += (double)__uint_as_float(a); }
        }
        __builtin_nontemporal_store(sv, &os[tid + j * 256]);
        __builtin_nontemporal_store(mv, &om[tid + j * 256]);
    }
    #pragma unroll
    for (int o = 32; o > 0; o >>= 1) {
        cnt += __shfl_down(cnt, o, 64);
        l1  += __shfl_down(l1,  o, 64);
    }
    if (lane == 0) { cnt_w[wid] = cnt; l1_w[wid] = l1; }
    __syncthreads();
    if (tid == 0) {
        int c    = cnt_w[0] + cnt_w[1] + cnt_w[2] + cnt_w[3];
        double l = l1_w[0] + l1_w[1] + l1_w[2] + l1_w[3];
        out_actual[row] = (float)c / 4096.0f;
        l1rows[row] = l;
    }
}

// ---------------- k3: deterministic l1 mean (f64), 1024 threads
__global__ __launch_bounds__(1024) void k3_l1(const double* __restrict__ l1rows,
                                              float* __restrict__ out_l1)
{
    __shared__ double sm[1024];
    int tid = threadIdx.x;
    double s = l1rows[tid] + l1rows[tid + 1024] + l1rows[tid + 2048] + l1rows[tid + 3072];
    sm[tid] = s;
    __syncthreads();
    for (int st = 512; st > 0; st >>= 1) {
        if (tid < st) sm[tid] += sm[tid + st];
        __syncthreads();
    }
    if (tid == 0) out_l1[0] = (float)(sm[0] / 4096.0);
}

extern "C" void kernel_launch(void* const* d_in, const int* in_sizes, int n_in,
                              void* d_out, int out_size, void* d_ws, size_t ws_size,
                              hipStream_t stream)
{
    const float* x  = (const float*)d_in[0];
    const float* W1 = (const float*)d_in[1];
    const float* b1 = (const float*)d_in[2];
    const float* W2 = (const float*)d_in[3];
    const float* b2 = (const float*)d_in[4];

    float* out        = (float*)d_out;
    float* out_sparse = out;                       // [4096,4096]
    float* out_mask   = out + 16777216;            // [4096,4096]
    float* out_spars  = out + 33554432;            // [4096,1]
    float* out_actual = out + 33558528;            // [4096]
    float* out_l1     = out + 33562624;            // [1]

    // big scratch inside d_out (fully consumed by k1est before k2b writes)
    unsigned char* xa_t = (unsigned char*)(out);             // 16MB fp8
    unsigned char* wb_t = (unsigned char*)(out + 4194304);   // 4MB fp8

    // small hot arrays in d_ws (read by k2a/k2b/k3 -> must not alias outputs)
    char* ws = (char*)d_ws;
    float*    plogit  = (float*)(ws);             // 256KB [4096][16]
    unsigned* thr_arr = (unsigned*)(ws + 262144); // 16KB
    double*   l1rows  = (double*)(ws + 278528);   // 32KB

    k0a_cvtx<<<dim3(64, 8), 256, 0, stream>>>(x, xa_t);
    k0b_cvtw<<<1024, 256, 0, stream>>>(W1, wb_t);
    k1est<<<512, 512, 0, stream>>>(xa_t, wb_t, b1, W2, plogit);
    k2a_sel<<<4096, 256, 0, stream>>>(x, plogit, b2, thr_arr, out_spars);
    k2b_apply<<<4096, 256, 0, stream>>>(x, thr_arr, out_sparse, out_mask,
                                        out_actual, l1rows);
    k3_l1<<<1, 1024, 0, stream>>>(l1rows, out_l1);
}

// Round 18
// 119.217 us; speedup vs baseline: 1.0154x; 1.0154x over previous
//
#include <hip/hip_runtime.h>
#include <hip/hip_fp8.h>

typedef __attribute__((ext_vector_type(4))) float f32x4;

// ---- d_out scratch (float offsets), consumed by k1est before k2 overwrites:
//   xa_t fp8[16777216B] -> floats [0, 4194304)        tiled [64 bm][128 kt][64 r][32 k] swz
//   wb_t fp8[ 4194304B] -> floats [4194304, 5242880)  tiled [ 8 bn][128 kt][128 n][32 k] swz (W1*64)
// ---- d_ws layout (bytes):
//   plogit f32[4096*16] [0, 262144)      exact relu'd N-partials (unique writer, bn*2+wn)
//   l1rows f64[4096]    [262144, 294912)

__device__ __forceinline__ unsigned char f2fp8(float f) {
    return (unsigned char)__hip_cvt_float_to_fp8(f, __HIP_SATFINITE, __HIP_E4M3);
}

__device__ __forceinline__ void gl16(const void* g, void* l) {
    __builtin_amdgcn_global_load_lds(
        (const __attribute__((address_space(1))) void*)g,
        (__attribute__((address_space(3))) void*)l, 16, 0, 0);
}

// ---------------- k0a: x (fp32 [4096][4096]) -> xa_t (fp8 e4m3, 64-row K-tiled + swz)
__global__ __launch_bounds__(256) void k0a_cvtx(const float* __restrict__ x,
                                                unsigned char* __restrict__ xa_t)
{
    const int bm = blockIdx.x;                // 0..63 (64-row group)
    const int ktbase = blockIdx.y * 16;       // 8 y-blocks x 16 kt
    const int t = threadIdx.x;
    const int rr = t >> 2, q = t & 3;         // row 0..63, k-oct 0..3
    const int kgp = q ^ ((rr >> 1) & 3);
    const size_t rowoff = (size_t)(bm * 64 + rr) * 4096;

    #pragma unroll
    for (int i = 0; i < 16; i++) {
        const int kt = ktbase + i;
        const float* src = x + rowoff + kt * 32 + q * 8;
        float4 v0 = *(const float4*)src;
        float4 v1 = *(const float4*)(src + 4);
        union { unsigned char c[8]; uint2 u; } o;
        o.c[0] = f2fp8(v0.x); o.c[1] = f2fp8(v0.y);
        o.c[2] = f2fp8(v0.z); o.c[3] = f2fp8(v0.w);
        o.c[4] = f2fp8(v1.x); o.c[5] = f2fp8(v1.y);
        o.c[6] = f2fp8(v1.z); o.c[7] = f2fp8(v1.w);
        *(uint2*)(xa_t + ((size_t)(bm * 128 + kt) * 64 + rr) * 32 + kgp * 8) = o.u;
    }
}

// ---------------- k0b: W1 [4096][1024] fp32 -> wb_t (fp8 of 64*W1, transposed tiled + swz)
__global__ __launch_bounds__(256) void k0b_cvtw(const float* __restrict__ W1,
                                                unsigned char* __restrict__ wb_t)
{
    __shared__ float ls[32][128];
    const int bx = blockIdx.x;                // 1024 = 8 bn x 128 kt
    const int bn = bx >> 7, kt = bx & 127;
    const int t = threadIdx.x;

    #pragma unroll
    for (int i = 0; i < 4; i++) {
        int s = t + i * 256;                  // 1024 float4 slots
        int r = s >> 5, c4 = s & 31;
        *(float4*)&ls[r][c4 * 4] =
            *(const float4*)(W1 + (size_t)(kt * 32 + r) * 1024 + bn * 128 + c4 * 4);
    }
    __syncthreads();

    const int n = t >> 1, half = t & 1;
    #pragma unroll
    for (int kg2 = 0; kg2 < 2; kg2++) {
        const int kg = half * 2 + kg2;
        const int kgp = kg ^ ((n >> 1) & 3);
        union { unsigned char c[8]; uint2 u; } o;
        #pragma unroll
        for (int j = 0; j < 8; j++) o.c[j] = f2fp8(ls[kg * 8 + j][n] * 64.0f);
        *(uint2*)(wb_t + (size_t)(bn * 128 + kt) * 4096 + n * 32 + kgp * 8) = o.u;
    }
}

// ---------------- k1est: fp8 MFMA, BM=64 x BN=128, FULL K (exact relu), N-split partials.
// 8 waves (512 thr): wave w -> rows (w&3)*16, cols (w>>2)*64. Waves 0-3 stage with
// counted vmcnt(6) quad-buffer schedule; waves 4-7 compute-only. R13-exact.
__global__ __launch_bounds__(512, 4) void k1est(const unsigned char* __restrict__ xa_t,
                                                const unsigned char* __restrict__ wb_t,
                                                const float* __restrict__ b1,
                                                const float* __restrict__ W2,
                                                float* __restrict__ plogit)
{
    __shared__ alignas(16) unsigned char Ab[4][4096];
    __shared__ alignas(16) unsigned char Bb[4][8192];

    const int bid = blockIdx.x;                      // 512 blocks
    const int wgid = (bid & 7) * 64 + (bid >> 3);    // bijective, XCD-chunked
    const int bn = wgid >> 6, bm = wgid & 63;        // one bn per XCD (L2-pinned W)
    const int tid = threadIdx.x;
    const int l = tid & 63, w = tid >> 6;
    const int wm = w & 3, wn = w >> 2;
    const int arow = l & 15, kg = l >> 4;
    const int kgs = kg ^ ((arow >> 1) & 3);
    const bool stager = (w < 4);                     // tid < 256

    const unsigned char* abase = xa_t + (size_t)bm * 128 * 2048;
    const unsigned char* bbase = wb_t + (size_t)bn * 128 * 4096;

    f32x4 acc[4];
    #pragma unroll
    for (int j = 0; j < 4; j++) acc[j] = (f32x4)0.0f;

#define ISSUE(step, buf)                                                          \
    if (stager) {                                                                 \
        gl16(abase + (size_t)(step) * 4096 + tid * 16, &Ab[buf][tid * 16]);       \
        gl16(bbase + (size_t)(step) * 8192 + tid * 16, &Bb[buf][tid * 16]);       \
        gl16(bbase + (size_t)(step) * 8192 + (256 + tid) * 16,                    \
             &Bb[buf][(256 + tid) * 16]);                                         \
    }

    ISSUE(0, 0);
    ISSUE(1, 1);

    for (int t = 0; t < 64; t++) {
        const int buf = t & 3;
        if (t <= 61) {
            ISSUE(t + 2, (t + 2) & 3);
            asm volatile("s_waitcnt vmcnt(6)" ::: "memory");
        } else if (t == 62) {
            asm volatile("s_waitcnt vmcnt(3)" ::: "memory");
        } else {
            asm volatile("s_waitcnt vmcnt(0)" ::: "memory");
        }
        __builtin_amdgcn_s_barrier();
        __builtin_amdgcn_sched_barrier(0);

        #pragma unroll
        for (int j = 0; j < 2; j++) {
            long af = *(const long*)&Ab[buf][j * 2048 + (wm * 16 + arow) * 32 + kgs * 8];
            #pragma unroll
            for (int nf = 0; nf < 4; nf++) {
                long bf = *(const long*)&Bb[buf][j * 4096 +
                                                 (wn * 64 + nf * 16 + arow) * 32 + kgs * 8];
                acc[nf] = __builtin_amdgcn_mfma_f32_16x16x32_fp8_fp8(af, bf, acc[nf], 0, 0, 0);
            }
        }
    }
#undef ISSUE

    // epilogue: EXACT relu over full-K h, dot W2 over this wave's 64 cols.
    // C/D layout (m89): col = lane&15 (N idx), row = (lane>>4)*4 + i (M idx)
    float p[4] = {0.0f, 0.0f, 0.0f, 0.0f};
    #pragma unroll
    for (int nf = 0; nf < 4; nf++) {
        const int n = bn * 128 + wn * 64 + nf * 16 + arow;
        const float bb = b1[n], ww = W2[n];
        #pragma unroll
        for (int i = 0; i < 4; i++) {
            float h = acc[nf][i] * 0.015625f + bb;   // undo W1*64 scale
            if (h > 0.0f) p[i] += h * ww;
        }
    }
    #pragma unroll
    for (int i = 0; i < 4; i++) {
        #pragma unroll
        for (int o = 1; o < 16; o <<= 1) p[i] += __shfl_xor(p[i], o, 64);
        if (arow == 0) {
            const int row = bm * 64 + wm * 16 + kg * 4 + i;
            plogit[(size_t)row * 16 + bn * 2 + wn] = p[i];   // unique writer
        }
    }
}

// ---------------- k2: fused per-row k + select + apply (R15 base). Select tail
// replaced: passes 1-3 (9 barrier phases) -> single O(nc^2/256) rank pass over
// the ~200 compacted candidates (ties by slot index -> same thr VALUE always).
__global__ __launch_bounds__(256) void k2_row(const float* __restrict__ x,
                                              const float* __restrict__ plogit,
                                              const float* __restrict__ b2,
                                              float* __restrict__ out_sparse,
                                              float* __restrict__ out_mask,
                                              float* __restrict__ out_spars,
                                              float* __restrict__ out_actual,
                                              double* __restrict__ l1rows)
{
    __shared__ unsigned hist[2048];
    __shared__ unsigned cand[512];
    __shared__ unsigned ccnt;
    __shared__ unsigned wsum[4];
    __shared__ int cnt_w[4];
    __shared__ double l1_w[4];
    __shared__ unsigned sel_s, selexc_s;
    __shared__ unsigned thr_s;
    __shared__ int k_s;

    const int row = blockIdx.x;
    const int tid = threadIdx.x;
    const int lane = tid & 63, wid = tid >> 6;
    const float* xr = x + (size_t)row * 4096;

    for (int i = tid; i < 2048; i += 256) hist[i] = 0;
    if (tid == 0) {
        float lg = 0.0f;
        #pragma unroll
        for (int t = 0; t < 16; t++) lg += plogit[(size_t)row * 16 + t];
        double s  = 1.0 / (1.0 + exp(-(double)(lg + b2[0])));
        double sp = 0.05 + 0.25 * s;
        int k = (int)rint(4096.0 * (1.0 - sp));
        if (k < 1) k = 1;
        if (k > 4096) k = 4096;
        k_s = k;
        ccnt = 0;
        out_spars[row] = (float)sp;
    }
    __syncthreads();

    // ---- load row into registers + pass-0 histogram (11-bit bins, bits 30:20)
    uint4 rv[4];
    #pragma unroll
    for (int j = 0; j < 4; j++) {
        rv[j] = ((const uint4*)xr)[tid + j * 256];
        atomicAdd(&hist[(rv[j].x & 0x7fffffffu) >> 20], 1u);
        atomicAdd(&hist[(rv[j].y & 0x7fffffffu) >> 20], 1u);
        atomicAdd(&hist[(rv[j].z & 0x7fffffffu) >> 20], 1u);
        atomicAdd(&hist[(rv[j].w & 0x7fffffffu) >> 20], 1u);
    }
    __syncthreads();

    int krem = k_s;
    unsigned prefix = 0;

    // ---- pass 0: scan 2048 bins, pick winning bin
    {
        const unsigned base = tid * 8;
        unsigned bl[8];
        unsigned v = 0;
        #pragma unroll
        for (int j = 0; j < 8; j++) { bl[j] = hist[base + j]; v += bl[j]; }
        unsigned sc = v;
        #pragma unroll
        for (int o = 1; o < 64; o <<= 1) {
            unsigned n = __shfl_up(sc, o, 64);
            if (lane >= o) sc += n;
        }
        if (lane == 63) wsum[wid] = sc;
        __syncthreads();
        unsigned off = 0;
        for (int ww = 0; ww < wid; ww++) off += wsum[ww];
        sc += off;
        unsigned exc = sc - v;
        if ((int)sc >= krem && (int)exc < krem) {
            unsigned run = exc;
            #pragma unroll
            for (int j = 0; j < 8; j++) {
                if ((int)run < krem && (int)(run + bl[j]) >= krem) {
                    sel_s = base + j; selexc_s = run;
                }
                run += bl[j];
            }
        }
        __syncthreads();
        prefix = sel_s;
        krem -= (int)selexc_s;
        __syncthreads();
    }

    // ---- compact candidates in the winning bin (atomic order; value-ties broken
    // by slot index, so the selected VALUE is order-independent)
    #pragma unroll
    for (int j = 0; j < 4; j++)
        #pragma unroll
        for (int e = 0; e < 4; e++) {
            unsigned a = (&rv[j].x)[e] & 0x7fffffffu;
            if ((a >> 20) == prefix) {
                unsigned s = atomicAdd(&ccnt, 1u);
                if (s < 512) cand[s] = a;
            }
        }
    __syncthreads();
    const int nc = (int)ccnt;
    unsigned thr;

    if (nc <= 512) {
        // ---- single rank pass: kth-smallest among nc candidates (1 barrier)
        for (int c = tid; c < nc; c += 256) {
            const unsigned v = cand[c];
            int rank = 0;
            for (int j = 0; j < nc; j++) {
                unsigned u = cand[j];
                rank += (u < v || (u == v && j < c)) ? 1 : 0;
            }
            if (rank == krem - 1) thr_s = v;
        }
        __syncthreads();
        thr = thr_s;
    } else {
        // ---- fallback (never for N(0,1) rows): 3-pass radix over registers
        #pragma unroll
        for (int p = 0; p < 3; p++) {
            const int shift = (p == 0) ? 12 : (p == 1) ? 4 : 0;
            const int width = (p == 2) ? 4 : 8;
            const int nb = 1 << width;
            const int topshift = shift + width;
            if (tid < nb) hist[tid] = 0;
            __syncthreads();
            #pragma unroll
            for (int j = 0; j < 4; j++)
                #pragma unroll
                for (int e = 0; e < 4; e++) {
                    unsigned a = (&rv[j].x)[e] & 0x7fffffffu;
                    if ((a >> topshift) == prefix)
                        atomicAdd(&hist[(a >> shift) & (nb - 1)], 1u);
                }
            __syncthreads();
            unsigned v = (tid < nb) ? hist[tid] : 0;
            unsigned sc = v;
            #pragma unroll
            for (int o = 1; o < 64; o <<= 1) {
                unsigned n = __shfl_up(sc, o, 64);
                if (lane >= o) sc += n;
            }
            if (lane == 63) wsum[wid] = sc;
            __syncthreads();
            unsigned off = 0;
            for (int ww = 0; ww < wid; ww++) off += wsum[ww];
            sc += off;
            unsigned exc = sc - v;
            if ((int)sc >= krem && (int)exc < krem) { sel_s = (unsigned)tid; selexc_s = exc; }
            __syncthreads();
            prefix = (prefix << width) | sel_s;
            krem -= (int)selexc_s;
            __syncthreads();
        }
        thr = prefix;
    }

    // ---- apply from registers; coalesced float4 stores
    int cnt = 0;
    double l1 = 0.0;
    float* os = out_sparse + (size_t)row * 4096;
    float* om = out_mask + (size_t)row * 4096;
    #pragma unroll
    for (int j = 0; j < 4; j++) {
        float4 sv, mv;
        #pragma unroll
        for (int e = 0; e < 4; e++) {
            unsigned b = (&rv[j].x)[e];
            unsigned a = b & 0x7fffffffu;
            bool m = a > thr;
            (&sv.x)[e] = m ? __uint_as_float(b) : 0.0f;
            (&mv.x)[e] = m ? 1.0f : 0.0f;
            if (m) { cnt++; l1 += (double)__uint_as_float(a); }
        }
        ((float4*)os)[tid + j * 256] = sv;
        ((float4*)om)[tid + j * 256] = mv;
    }
    #pragma unroll
    for (int o = 32; o > 0; o >>= 1) {
        cnt += __shfl_down(cnt, o, 64);
        l1  += __shfl_down(l1,  o, 64);
    }
    if (lane == 0) { cnt_w[wid] = cnt; l1_w[wid] = l1; }
    __syncthreads();
    if (tid == 0) {
        int c    = cnt_w[0] + cnt_w[1] + cnt_w[2] + cnt_w[3];
        double l = l1_w[0] + l1_w[1] + l1_w[2] + l1_w[3];
        out_actual[row] = (float)c / 4096.0f;
        l1rows[row] = l;
    }
}

// ---------------- k3: deterministic l1 mean (f64), 1024 threads
__global__ __launch_bounds__(1024) void k3_l1(const double* __restrict__ l1rows,
                                              float* __restrict__ out_l1)
{
    __shared__ double sm[1024];
    int tid = threadIdx.x;
    double s = l1rows[tid] + l1rows[tid + 1024] + l1rows[tid + 2048] + l1rows[tid + 3072];
    sm[tid] = s;
    __syncthreads();
    for (int st = 512; st > 0; st >>= 1) {
        if (tid < st) sm[tid] += sm[tid + st];
        __syncthreads();
    }
    if (tid == 0) out_l1[0] = (float)(sm[0] / 4096.0);
}

extern "C" void kernel_launch(void* const* d_in, const int* in_sizes, int n_in,
                              void* d_out, int out_size, void* d_ws, size_t ws_size,
                              hipStream_t stream)
{
    const float* x  = (const float*)d_in[0];
    const float* W1 = (const float*)d_in[1];
    const float* b1 = (const float*)d_in[2];
    const float* W2 = (const float*)d_in[3];
    const float* b2 = (const float*)d_in[4];

    float* out        = (float*)d_out;
    float* out_sparse = out;                       // [4096,4096]
    float* out_mask   = out + 16777216;            // [4096,4096]
    float* out_spars  = out + 33554432;            // [4096,1]
    float* out_actual = out + 33558528;            // [4096]
    float* out_l1     = out + 33562624;            // [1]

    // big scratch inside d_out (fully consumed by k1est before k2 writes)
    unsigned char* xa_t = (unsigned char*)(out);             // 16MB fp8
    unsigned char* wb_t = (unsigned char*)(out + 4194304);   // 4MB fp8

    // small hot arrays in d_ws (read by k2/k3 -> must not alias outputs)
    char* ws = (char*)d_ws;
    float*  plogit = (float*)(ws);             // 256KB [4096][16]
    double* l1rows = (double*)(ws + 262144);   // 32KB

    k0a_cvtx<<<dim3(64, 8), 256, 0, stream>>>(x, xa_t);
    k0b_cvtw<<<1024, 256, 0, stream>>>(W1, wb_t);
    k1est<<<512, 512, 0, stream>>>(xa_t, wb_t, b1, W2, plogit);
    k2_row<<<4096, 256, 0, stream>>>(x, plogit, b2, out_sparse, out_mask,
                                     out_spars, out_actual, l1rows);
    k3_l1<<<1, 1024, 0, stream>>>(l1rows, out_l1);
}

// Round 19
// 109.515 us; speedup vs baseline: 1.1053x; 1.0886x over previous
//
#include <hip/hip_runtime.h>
#include <hip/hip_fp8.h>

typedef __attribute__((ext_vector_type(4))) float f32x4;

// ---- d_out scratch (float offsets), consumed by k1est before k2 overwrites:
//   xa_t fp8[16777216B] -> floats [0, 4194304)        tiled [64 bm][128 kt][64 r][32 k] swz
//   wb_t fp8[ 4194304B] -> floats [4194304, 5242880)  tiled [ 8 bn][128 kt][128 n][32 k] swz (W1*64)
// ---- d_ws layout (bytes):
//   plogit f32[4096*16] [0, 262144)      exact relu'd N-partials (unique writer, bn*2+wn)
//   l1rows f64[4096]    [262144, 294912)

__device__ __forceinline__ unsigned char f2fp8(float f) {
    return (unsigned char)__hip_cvt_float_to_fp8(f, __HIP_SATFINITE, __HIP_E4M3);
}

__device__ __forceinline__ void gl16(const void* g, void* l) {
    __builtin_amdgcn_global_load_lds(
        (const __attribute__((address_space(1))) void*)g,
        (__attribute__((address_space(3))) void*)l, 16, 0, 0);
}

// ---------------- k0a: x (fp32 [4096][4096]) -> xa_t (fp8 e4m3, 64-row K-tiled + swz)
__global__ __launch_bounds__(256) void k0a_cvtx(const float* __restrict__ x,
                                                unsigned char* __restrict__ xa_t)
{
    const int bm = blockIdx.x;                // 0..63 (64-row group)
    const int ktbase = blockIdx.y * 16;       // 8 y-blocks x 16 kt
    const int t = threadIdx.x;
    const int rr = t >> 2, q = t & 3;         // row 0..63, k-oct 0..3
    const int kgp = q ^ ((rr >> 1) & 3);
    const size_t rowoff = (size_t)(bm * 64 + rr) * 4096;

    #pragma unroll
    for (int i = 0; i < 16; i++) {
        const int kt = ktbase + i;
        const float* src = x + rowoff + kt * 32 + q * 8;
        float4 v0 = *(const float4*)src;
        float4 v1 = *(const float4*)(src + 4);
        union { unsigned char c[8]; uint2 u; } o;
        o.c[0] = f2fp8(v0.x); o.c[1] = f2fp8(v0.y);
        o.c[2] = f2fp8(v0.z); o.c[3] = f2fp8(v0.w);
        o.c[4] = f2fp8(v1.x); o.c[5] = f2fp8(v1.y);
        o.c[6] = f2fp8(v1.z); o.c[7] = f2fp8(v1.w);
        *(uint2*)(xa_t + ((size_t)(bm * 128 + kt) * 64 + rr) * 32 + kgp * 8) = o.u;
    }
}

// ---------------- k0b: W1 [4096][1024] fp32 -> wb_t (fp8 of 64*W1, transposed tiled + swz)
__global__ __launch_bounds__(256) void k0b_cvtw(const float* __restrict__ W1,
                                                unsigned char* __restrict__ wb_t)
{
    __shared__ float ls[32][128];
    const int bx = blockIdx.x;                // 1024 = 8 bn x 128 kt
    const int bn = bx >> 7, kt = bx & 127;
    const int t = threadIdx.x;

    #pragma unroll
    for (int i = 0; i < 4; i++) {
        int s = t + i * 256;                  // 1024 float4 slots
        int r = s >> 5, c4 = s & 31;
        *(float4*)&ls[r][c4 * 4] =
            *(const float4*)(W1 + (size_t)(kt * 32 + r) * 1024 + bn * 128 + c4 * 4);
    }
    __syncthreads();

    const int n = t >> 1, half = t & 1;
    #pragma unroll
    for (int kg2 = 0; kg2 < 2; kg2++) {
        const int kg = half * 2 + kg2;
        const int kgp = kg ^ ((n >> 1) & 3);
        union { unsigned char c[8]; uint2 u; } o;
        #pragma unroll
        for (int j = 0; j < 8; j++) o.c[j] = f2fp8(ls[kg * 8 + j][n] * 64.0f);
        *(uint2*)(wb_t + (size_t)(bn * 128 + kt) * 4096 + n * 32 + kgp * 8) = o.u;
    }
}

// ---------------- k1est: fp8 MFMA, BM=64 x BN=128, FULL K (exact relu), N-split partials.
// 8 waves (512 thr): wave w -> rows (w&3)*16, cols (w>>2)*64. Waves 0-3 stage with
// counted vmcnt(6) quad-buffer schedule; waves 4-7 compute-only.
__global__ __launch_bounds__(512, 4) void k1est(const unsigned char* __restrict__ xa_t,
                                                const unsigned char* __restrict__ wb_t,
                                                const float* __restrict__ b1,
                                                const float* __restrict__ W2,
                                                float* __restrict__ plogit)
{
    __shared__ alignas(16) unsigned char Ab[4][4096];
    __shared__ alignas(16) unsigned char Bb[4][8192];

    const int bid = blockIdx.x;                      // 512 blocks
    const int wgid = (bid & 7) * 64 + (bid >> 3);    // bijective, XCD-chunked
    const int bn = wgid >> 6, bm = wgid & 63;        // one bn per XCD (L2-pinned W)
    const int tid = threadIdx.x;
    const int l = tid & 63, w = tid >> 6;
    const int wm = w & 3, wn = w >> 2;
    const int arow = l & 15, kg = l >> 4;
    const int kgs = kg ^ ((arow >> 1) & 3);
    const bool stager = (w < 4);                     // tid < 256

    const unsigned char* abase = xa_t + (size_t)bm * 128 * 2048;
    const unsigned char* bbase = wb_t + (size_t)bn * 128 * 4096;

    f32x4 acc[4];
    #pragma unroll
    for (int j = 0; j < 4; j++) acc[j] = (f32x4)0.0f;

#define ISSUE(step, buf)                                                          \
    if (stager) {                                                                 \
        gl16(abase + (size_t)(step) * 4096 + tid * 16, &Ab[buf][tid * 16]);       \
        gl16(bbase + (size_t)(step) * 8192 + tid * 16, &Bb[buf][tid * 16]);       \
        gl16(bbase + (size_t)(step) * 8192 + (256 + tid) * 16,                    \
             &Bb[buf][(256 + tid) * 16]);                                         \
    }

    ISSUE(0, 0);
    ISSUE(1, 1);

    for (int t = 0; t < 64; t++) {
        const int buf = t & 3;
        if (t <= 61) {
            ISSUE(t + 2, (t + 2) & 3);
            asm volatile("s_waitcnt vmcnt(6)" ::: "memory");
        } else if (t == 62) {
            asm volatile("s_waitcnt vmcnt(3)" ::: "memory");
        } else {
            asm volatile("s_waitcnt vmcnt(0)" ::: "memory");
        }
        __builtin_amdgcn_s_barrier();
        __builtin_amdgcn_sched_barrier(0);

        #pragma unroll
        for (int j = 0; j < 2; j++) {
            long af = *(const long*)&Ab[buf][j * 2048 + (wm * 16 + arow) * 32 + kgs * 8];
            #pragma unroll
            for (int nf = 0; nf < 4; nf++) {
                long bf = *(const long*)&Bb[buf][j * 4096 +
                                                 (wn * 64 + nf * 16 + arow) * 32 + kgs * 8];
                acc[nf] = __builtin_amdgcn_mfma_f32_16x16x32_fp8_fp8(af, bf, acc[nf], 0, 0, 0);
            }
        }
    }
#undef ISSUE

    // epilogue: EXACT relu over full-K h, dot W2 over this wave's 64 cols.
    // C/D layout (m89): col = lane&15 (N idx), row = (lane>>4)*4 + i (M idx)
    float p[4] = {0.0f, 0.0f, 0.0f, 0.0f};
    #pragma unroll
    for (int nf = 0; nf < 4; nf++) {
        const int n = bn * 128 + wn * 64 + nf * 16 + arow;
        const float bb = b1[n], ww = W2[n];
        #pragma unroll
        for (int i = 0; i < 4; i++) {
            float h = acc[nf][i] * 0.015625f + bb;   // undo W1*64 scale
            if (h > 0.0f) p[i] += h * ww;
        }
    }
    #pragma unroll
    for (int i = 0; i < 4; i++) {
        #pragma unroll
        for (int o = 1; o < 16; o <<= 1) p[i] += __shfl_xor(p[i], o, 64);
        if (arow == 0) {
            const int row = bm * 64 + wm * 16 + kg * 4 + i;
            plogit[(size_t)row * 16 + bn * 2 + wn] = p[i];   // unique writer
        }
    }
}

// ---------------- k2: per-row k + radix select + outputs, row register-cached.
// R15-exact: radix 11+8+8+4, scan-based compaction, fused apply.
__global__ __launch_bounds__(256) void k2_row(const float* __restrict__ x,
                                              const float* __restrict__ plogit,
                                              const float* __restrict__ b2,
                                              float* __restrict__ out_sparse,
                                              float* __restrict__ out_mask,
                                              float* __restrict__ out_spars,
                                              float* __restrict__ out_actual,
                                              double* __restrict__ l1rows)
{
    __shared__ unsigned hist[2048];
    __shared__ unsigned cand[512];
    __shared__ unsigned wsum[4];
    __shared__ int cnt_w[4];
    __shared__ double l1_w[4];
    __shared__ unsigned sel_s, selexc_s;
    __shared__ int k_s;

    const int row = blockIdx.x;
    const int tid = threadIdx.x;
    const int lane = tid & 63, wid = tid >> 6;
    const float* xr = x + (size_t)row * 4096;

    for (int i = tid; i < 2048; i += 256) hist[i] = 0;
    if (tid == 0) {
        float lg = 0.0f;
        #pragma unroll
        for (int t = 0; t < 16; t++) lg += plogit[(size_t)row * 16 + t];
        double s  = 1.0 / (1.0 + exp(-(double)(lg + b2[0])));
        double sp = 0.05 + 0.25 * s;
        int k = (int)rint(4096.0 * (1.0 - sp));
        if (k < 1) k = 1;
        if (k > 4096) k = 4096;
        k_s = k;
        out_spars[row] = (float)sp;
    }
    __syncthreads();

    // ---- load row into registers + pass-0 histogram (11-bit bins, bits 30:20)
    uint4 rv[4];
    #pragma unroll
    for (int j = 0; j < 4; j++) {
        rv[j] = ((const uint4*)xr)[tid + j * 256];
        atomicAdd(&hist[(rv[j].x & 0x7fffffffu) >> 20], 1u);
        atomicAdd(&hist[(rv[j].y & 0x7fffffffu) >> 20], 1u);
        atomicAdd(&hist[(rv[j].z & 0x7fffffffu) >> 20], 1u);
        atomicAdd(&hist[(rv[j].w & 0x7fffffffu) >> 20], 1u);
    }
    __syncthreads();

    int krem = k_s;
    unsigned prefix = 0;
    {
        const unsigned base = tid * 8;
        unsigned bl[8];
        unsigned v = 0;
        #pragma unroll
        for (int j = 0; j < 8; j++) { bl[j] = hist[base + j]; v += bl[j]; }
        unsigned sc = v;
        #pragma unroll
        for (int o = 1; o < 64; o <<= 1) {
            unsigned n = __shfl_up(sc, o, 64);
            if (lane >= o) sc += n;
        }
        if (lane == 63) wsum[wid] = sc;
        __syncthreads();
        unsigned off = 0;
        for (int ww = 0; ww < wid; ww++) off += wsum[ww];
        sc += off;
        unsigned exc = sc - v;
        if ((int)sc >= krem && (int)exc < krem) {
            unsigned run = exc;
            #pragma unroll
            for (int j = 0; j < 8; j++) {
                if ((int)run < krem && (int)(run + bl[j]) >= krem) {
                    sel_s = base + j; selexc_s = run;
                }
                run += bl[j];
            }
        }
        __syncthreads();
        prefix = sel_s;
        krem -= (int)selexc_s;
        __syncthreads();
    }

    // ---- compact candidates matching the 11-bit prefix via exact block scan
    int cntm = 0;
    #pragma unroll
    for (int j = 0; j < 4; j++)
        #pragma unroll
        for (int e = 0; e < 4; e++) {
            unsigned a = (&rv[j].x)[e] & 0x7fffffffu;
            if ((a >> 20) == prefix) cntm++;
        }
    unsigned sc2 = (unsigned)cntm;
    #pragma unroll
    for (int o = 1; o < 64; o <<= 1) {
        unsigned n = __shfl_up(sc2, o, 64);
        if (lane >= o) sc2 += n;
    }
    if (lane == 63) wsum[wid] = sc2;
    __syncthreads();
    unsigned off2 = 0;
    for (int ww = 0; ww < wid; ww++) off2 += wsum[ww];
    unsigned pos = sc2 + off2 - (unsigned)cntm;     // exclusive prefix
    const int nc = (int)(wsum[0] + wsum[1] + wsum[2] + wsum[3]);
    #pragma unroll
    for (int j = 0; j < 4; j++)
        #pragma unroll
        for (int e = 0; e < 4; e++) {
            unsigned a = (&rv[j].x)[e] & 0x7fffffffu;
            if ((a >> 20) == prefix) { if (pos < 512) cand[pos] = a; pos++; }
        }
    __syncthreads();
    const bool usec = (nc <= 512);

    // ---- passes 1-3: 8/8/4 bits among prefix-matched elements
    #pragma unroll
    for (int p = 0; p < 3; p++) {
        const int shift = (p == 0) ? 12 : (p == 1) ? 4 : 0;
        const int width = (p == 2) ? 4 : 8;
        const int nb = 1 << width;
        const int topshift = shift + width;
        if (tid < nb) hist[tid] = 0;
        __syncthreads();
        if (usec) {
            for (int i = tid; i < nc; i += 256) {
                unsigned a = cand[i];
                if ((a >> topshift) == prefix)
                    atomicAdd(&hist[(a >> shift) & (nb - 1)], 1u);
            }
        } else {
            #pragma unroll
            for (int j = 0; j < 4; j++) {
                #pragma unroll
                for (int e = 0; e < 4; e++) {
                    unsigned a = (&rv[j].x)[e] & 0x7fffffffu;
                    if ((a >> topshift) == prefix)
                        atomicAdd(&hist[(a >> shift) & (nb - 1)], 1u);
                }
            }
        }
        __syncthreads();
        unsigned v = (tid < nb) ? hist[tid] : 0;
        unsigned sc = v;
        #pragma unroll
        for (int o = 1; o < 64; o <<= 1) {
            unsigned n = __shfl_up(sc, o, 64);
            if (lane >= o) sc += n;
        }
        if (lane == 63) wsum[wid] = sc;
        __syncthreads();
        unsigned off = 0;
        for (int ww = 0; ww < wid; ww++) off += wsum[ww];
        sc += off;
        unsigned exc = sc - v;
        if ((int)sc >= krem && (int)exc < krem) { sel_s = (unsigned)tid; selexc_s = exc; }
        __syncthreads();
        prefix = (prefix << width) | sel_s;
        krem -= (int)selexc_s;
        __syncthreads();
    }
    const unsigned thr = prefix;   // bit pattern of kth smallest |x| (31 bits)

    // ---- apply from registers; coalesced float4 stores
    int cnt = 0;
    double l1 = 0.0;
    float* os = out_sparse + (size_t)row * 4096;
    float* om = out_mask + (size_t)row * 4096;
    #pragma unroll
    for (int j = 0; j < 4; j++) {
        float4 sv, mv;
        #pragma unroll
        for (int e = 0; e < 4; e++) {
            unsigned b = (&rv[j].x)[e];
            unsigned a = b & 0x7fffffffu;
            bool m = a > thr;
            (&sv.x)[e] = m ? __uint_as_float(b) : 0.0f;
            (&mv.x)[e] = m ? 1.0f : 0.0f;
            if (m) { cnt++; l1 += (double)__uint_as_float(a); }
        }
        ((float4*)os)[tid + j * 256] = sv;
        ((float4*)om)[tid + j * 256] = mv;
    }
    #pragma unroll
    for (int o = 32; o > 0; o >>= 1) {
        cnt += __shfl_down(cnt, o, 64);
        l1  += __shfl_down(l1,  o, 64);
    }
    if (lane == 0) { cnt_w[wid] = cnt; l1_w[wid] = l1; }
    __syncthreads();
    if (tid == 0) {
        int c    = cnt_w[0] + cnt_w[1] + cnt_w[2] + cnt_w[3];
        double l = l1_w[0] + l1_w[1] + l1_w[2] + l1_w[3];
        out_actual[row] = (float)c / 4096.0f;
        l1rows[row] = l;
    }
}

// ---------------- k3: deterministic l1 mean (f64), 1024 threads
__global__ __launch_bounds__(1024) void k3_l1(const double* __restrict__ l1rows,
                                              float* __restrict__ out_l1)
{
    __shared__ double sm[1024];
    int tid = threadIdx.x;
    double s = l1rows[tid] + l1rows[tid + 1024] + l1rows[tid + 2048] + l1rows[tid + 3072];
    sm[tid] = s;
    __syncthreads();
    for (int st = 512; st > 0; st >>= 1) {
        if (tid < st) sm[tid] += sm[tid + st];
        __syncthreads();
    }
    if (tid == 0) out_l1[0] = (float)(sm[0] / 4096.0);
}

extern "C" void kernel_launch(void* const* d_in, const int* in_sizes, int n_in,
                              void* d_out, int out_size, void* d_ws, size_t ws_size,
                              hipStream_t stream)
{
    const float* x  = (const float*)d_in[0];
    const float* W1 = (const float*)d_in[1];
    const float* b1 = (const float*)d_in[2];
    const float* W2 = (const float*)d_in[3];
    const float* b2 = (const float*)d_in[4];

    float* out        = (float*)d_out;
    float* out_sparse = out;                       // [4096,4096]
    float* out_mask   = out + 16777216;            // [4096,4096]
    float* out_spars  = out + 33554432;            // [4096,1]
    float* out_actual = out + 33558528;            // [4096]
    float* out_l1     = out + 33562624;            // [1]

    // big scratch inside d_out (fully consumed by k1est before k2 writes)
    unsigned char* xa_t = (unsigned char*)(out);             // 16MB fp8
    unsigned char* wb_t = (unsigned char*)(out + 4194304);   // 4MB fp8

    // small hot arrays in d_ws (read by k2/k3 -> must not alias outputs)
    char* ws = (char*)d_ws;
    float*  plogit = (float*)(ws);             // 256KB [4096][16]
    double* l1rows = (double*)(ws + 262144);   // 32KB

    k0a_cvtx<<<dim3(64, 8), 256, 0, stream>>>(x, xa_t);
    k0b_cvtw<<<1024, 256, 0, stream>>>(W1, wb_t);
    k1est<<<512, 512, 0, stream>>>(xa_t, wb_t, b1, W2, plogit);
    k2_row<<<4096, 256, 0, stream>>>(x, plogit, b2, out_sparse, out_mask,
                                     out_spars, out_actual, l1rows);
    k3_l1<<<1, 1024, 0, stream>>>(l1rows, out_l1);
}